// Round 1
// baseline (81.673 us; speedup 1.0000x reference)
//
#include <hip/hip_runtime.h>

#define TT 200
#define UU 200
#define VV 512
#define BB 8
#define NEGF (-1e30f)

// Banded RNNT forward DP.
// Band-local lane layout: at step t, lane l (0..10) owns u = t-5+l.
// alpha[t][u] = ecum[t][u] + log2 sum_{u'=t-5..min(u,t+4)} 2^( alpha[t-1][u'] + pb[t-1][u'] - ecum[t][u'] )
// where ecum here is band-relative (exclusive prefix over L[t, t-5 .. ]),
// all values pre-scaled by log2(e) so exp/log are native v_exp_f32/v_log_f32.
__global__ __launch_bounds__(256) void rnnt_banded(
    const float* __restrict__ lp,
    const int* __restrict__ targets,
    const int* __restrict__ logit_lengths,
    const int* __restrict__ target_lengths,
    float* __restrict__ out)
{
    __shared__ float Ls[TT][16];   // Ls[t][l] = log2e * lp[t, t-5+l, tgt[t-5+l]]  (0 if u out of range)
    __shared__ float Ps[TT][16];   // Ps[t][l] = log2e * lp[t, t-4+l, 0]           (0 if u out of range)
    __shared__ float Ce[TT][16];   // Ce[t][l] = sum_{i<l} Ls[t][i]   (exclusive prefix)
    __shared__ float Wc[TT][16];   // Wc[t][l] = Ps[t-1][l] - Ce[t][l]
    __shared__ int   tgt_s[UU];

    const int b   = blockIdx.x;
    const int tid = threadIdx.x;
    const float LOG2E = 1.4426950408889634f;

    const float* __restrict__ lpb = lp + (size_t)b * TT * UU * VV;

    if (tid < UU) tgt_s[tid] = targets[b * UU + tid];
    __syncthreads();

    // ---- Phase 1: gather band values (24 slots per t: 12 L, 12 pb) ----
    // 200*24 = 4800 elements, 19 unrolled rounds of 256 -> loads stay in flight.
    #pragma unroll
    for (int it = 0; it < 19; ++it) {
        int idx  = tid + it * 256;
        bool live = idx < TT * 24;
        int t = idx / 24;
        int r = idx - t * 24;
        bool isL = r < 12;
        int l = isL ? r : r - 12;
        int u = t + l + (isL ? -5 : -4);
        bool ok = live && (u >= 0) && (u < UU);
        float val = 0.0f;
        if (ok) {
            int v = isL ? tgt_s[u] : 0;
            val = lpb[((size_t)t * UU + u) * VV + v] * LOG2E;
        }
        if (live) {
            if (isL) Ls[t][l] = val;
            else     Ps[t][l] = val;
        }
    }
    __syncthreads();

    // ---- Phase 1.5: per-row exclusive prefix sums + W rows (prev-independent) ----
    {
        int g = tid >> 4;     // 16 groups of 16 lanes
        int l = tid & 15;
        for (int t = g; t < TT; t += 16) {
            float lv = (l < 12) ? Ls[t][l] : 0.0f;
            float cin = lv;
            #pragma unroll
            for (int d = 1; d < 16; d <<= 1) {
                float o = __shfl_up(cin, d, 16);
                if (l >= d) cin += o;
            }
            float cexc = cin - lv;           // exclusive prefix
            Ce[t][l] = cexc;
            float pv = (t >= 1 && l < 12) ? Ps[t - 1][l] : 0.0f;
            Wc[t][l] = pv - cexc;
        }
    }
    __syncthreads();

    if (tid >= 64) return;   // DP on wave 0 only (4 redundant width-16 groups)

    const int tlen = logit_lengths[b];
    const int ulen = target_lengths[b];
    const int l = tid & 15;

    // init t=0: alpha[0, u] = ecum[0,u] for u in [0,5]; lane l owns u = l-5.
    // Ce[0][l] = sum_{k=0}^{l-6} L[0,k] exactly (invalid-u slots gathered as 0).
    float prev = (l >= 5 && l <= 10) ? Ce[0][l] : NEGF;

    for (int t = 1; t <= tlen; ++t) {
        // prevs[l] = alpha[t-1, t-5+l]  (shift: prev lane l owned u = t-6+l)
        float prevs = __shfl_down(prev, 1, 16);   // lane 15 clamps to own (NEG) — fine
        float w = prevs + Wc[t][l];

        // global max over the 16-lane group (butterfly)
        float m = w;
        #pragma unroll
        for (int d = 1; d < 16; d <<= 1) {
            float o = __shfl_xor(m, d, 16);
            m = fmaxf(m, o);
        }

        float e = exp2f(w - m);                    // NEG lanes -> 0
        // inclusive prefix-sum scan
        #pragma unroll
        for (int d = 1; d < 16; d <<= 1) {
            float o = __shfl_up(e, d, 16);
            if (l >= d) e += o;
        }

        float a = Ce[t][l] + m + __log2f(e);
        int u = t - 5 + l;
        if (l > 10 || u < 0 || u >= UU) a = NEGF;
        prev = a;
    }

    // loss_b = -alpha[tlen][ulen]; lane owning ulen is l* = ulen - tlen + 5 in [0,5]
    int lstar = ulen - tlen + 5;
    if (tid == lstar) {
        const float LN2 = 0.6931471805599453f;
        atomicAdd(out, -prev * (LN2 / (float)BB));
    }
}

extern "C" void kernel_launch(void* const* d_in, const int* in_sizes, int n_in,
                              void* d_out, int out_size, void* d_ws, size_t ws_size,
                              hipStream_t stream) {
    const float* lp  = (const float*)d_in[0];
    const int* tgt   = (const int*)d_in[1];
    const int* llen  = (const int*)d_in[2];
    const int* tlen  = (const int*)d_in[3];
    float* out = (float*)d_out;

    hipMemsetAsync(out, 0, sizeof(float), stream);
    rnnt_banded<<<BB, 256, 0, stream>>>(lp, tgt, llen, tlen, out);
}

// Round 2
// 36.704 us; speedup vs baseline: 2.2252x; 2.2252x over previous
//
#include <hip/hip_runtime.h>

#define TT 200
#define UU 200
#define VV 512
#define BB 8
#define NEGF (-1e30f)

// ---- DPP helpers (all cross-lane ops stay in the VALU pipe, ~2-5cy) ----
#define DPP_QUAD_XOR1       0xB1   // quad_perm [1,0,3,2]  : lane ^= 1
#define DPP_QUAD_XOR2       0x4E   // quad_perm [2,3,0,1]  : lane ^= 2
#define DPP_ROW_SHL1        0x101  // lane l <- l+1 (within row of 16)
#define DPP_ROW_SHR1        0x111  // lane l <- l-1
#define DPP_ROW_SHR2        0x112
#define DPP_ROW_SHR4        0x114
#define DPP_ROW_SHR8        0x118
#define DPP_ROW_MIRROR      0x140  // lane l <- 15-l
#define DPP_ROW_HALF_MIRROR 0x141  // lane l <- (l&8) | (7-(l&7))

template<int CTRL, bool ZERO>
__device__ __forceinline__ float fdpp(float src, float oldv) {
    return __int_as_float(__builtin_amdgcn_update_dpp(
        __float_as_int(oldv), __float_as_int(src), CTRL, 0xF, 0xF, ZERO));
}

// max over each 16-lane row, result in every lane of the row
__device__ __forceinline__ float max16(float x) {
    x = fmaxf(x, fdpp<DPP_QUAD_XOR1, true>(x, x));
    x = fmaxf(x, fdpp<DPP_QUAD_XOR2, true>(x, x));        // quads uniform
    x = fmaxf(x, fdpp<DPP_ROW_HALF_MIRROR, true>(x, x));  // 8-groups uniform
    x = fmaxf(x, fdpp<DPP_ROW_MIRROR, true>(x, x));       // row uniform
    return x;
}

// inclusive prefix sum within each 16-lane row (zero shifted in: bit-exact
// vs. predicated shfl_up variant for our values)
__device__ __forceinline__ float scan16(float x) {
    x += fdpp<DPP_ROW_SHR1, true>(x, x);
    x += fdpp<DPP_ROW_SHR2, true>(x, x);
    x += fdpp<DPP_ROW_SHR4, true>(x, x);
    x += fdpp<DPP_ROW_SHR8, true>(x, x);
    return x;
}

// Banded RNNT forward DP. Band-local lane layout: at step t, lane l (0..10)
// owns u = t-5+l. All values pre-scaled by log2(e) so exp/log are native
// v_exp_f32 / v_log_f32.
__global__ __launch_bounds__(256) void rnnt_banded(
    const float* __restrict__ lp,
    const int* __restrict__ targets,
    const int* __restrict__ logit_lengths,
    const int* __restrict__ target_lengths,
    float* __restrict__ out)
{
    __shared__ float Ls[TT][16];          // log2e * lp[t, t-5+l, tgt[u]]
    __shared__ float Ps[TT][16];          // log2e * lp[t, t-4+l, 0]
    __shared__ float Ce[(TT + 1) * 16];   // exclusive prefix of Ls row (pad row: dead prefetch)
    __shared__ float Wc[(TT + 1) * 16];   // Ps[t-1][l] - Ce[t][l]
    __shared__ int   tgt_s[UU];

    const int b   = blockIdx.x;
    const int tid = threadIdx.x;
    const float LOG2E = 1.4426950408889634f;

    const float* __restrict__ lpb = lp + (size_t)b * TT * UU * VV;

    if (tid < UU) tgt_s[tid] = targets[b * UU + tid];
    __syncthreads();

    // ---- Phase 1: gather band values (24 slots per t: 12 L, 12 pb) ----
    #pragma unroll
    for (int it = 0; it < 19; ++it) {
        int idx  = tid + it * 256;
        bool live = idx < TT * 24;
        int t = idx / 24;
        int r = idx - t * 24;
        bool isL = r < 12;
        int l = isL ? r : r - 12;
        int u = t + l + (isL ? -5 : -4);
        bool ok = live && (u >= 0) && (u < UU);
        float val = 0.0f;
        if (ok) {
            int v = isL ? tgt_s[u] : 0;
            val = lpb[((size_t)t * UU + u) * VV + v] * LOG2E;
        }
        if (live) {
            if (isL) Ls[t][l] = val;
            else     Ps[t][l] = val;
        }
    }
    __syncthreads();

    // ---- Phase 1.5: per-row exclusive prefix sums + W rows ----
    {
        int g = tid >> 4;     // 16 groups of 16 lanes
        int l = tid & 15;
        for (int t = g; t < TT; t += 16) {
            float lv = (l < 12) ? Ls[t][l] : 0.0f;
            float cin = scan16(lv);
            float cexc = cin - lv;           // exclusive prefix
            Ce[t * 16 + l] = cexc;
            float pv = (t >= 1 && l < 12) ? Ps[t - 1][l] : 0.0f;
            Wc[t * 16 + l] = pv - cexc;
        }
    }
    __syncthreads();

    if (tid >= 64) return;   // DP on wave 0 only (4 redundant 16-lane rows)

    const int tlen = logit_lengths[b];
    const int ulen = target_lengths[b];
    const int l = tid & 15;

    // init t=0: alpha[0, u] = ecum[0,u] for u in [0,5]; lane l owns u = l-5.
    float prev = (l >= 5 && l <= 10) ? Ce[0 + l] : NEGF;

    // prefetched LDS operands (keep LDS latency off the serial chain)
    float wc = Wc[1 * 16 + l];
    float ce = Ce[1 * 16 + l];

    for (int t = 1; t <= tlen; ++t) {
        float wc_n = Wc[(t + 1) * 16 + l];   // row TT pad: dead value on last iter
        float ce_n = Ce[(t + 1) * 16 + l];

        // prevs[l] = alpha[t-1, t-5+l]; lane 15 keeps own (NEG) like shfl_down clamp
        float prevs = fdpp<DPP_ROW_SHL1, false>(prev, prev);
        float w = prevs + wc;

        float m = max16(w);
        float e = __builtin_amdgcn_exp2f(w - m);
        e = scan16(e);                        // inclusive prefix sum
        float a = ce + m + __builtin_amdgcn_logf(e);   // v_log_f32 = log2

        int u = t - 5 + l;
        bool valid = (l <= 10) && (u >= 0) && (u < UU);
        prev = valid ? a : NEGF;

        wc = wc_n; ce = ce_n;
    }

    // loss_b = -alpha[tlen][ulen]; lane owning ulen is l* = ulen - tlen + 5 in [0,5]
    int lstar = ulen - tlen + 5;
    if (tid == lstar) {
        const float LN2 = 0.6931471805599453f;
        atomicAdd(out, -prev * (LN2 / (float)BB));
    }
}

extern "C" void kernel_launch(void* const* d_in, const int* in_sizes, int n_in,
                              void* d_out, int out_size, void* d_ws, size_t ws_size,
                              hipStream_t stream) {
    const float* lp  = (const float*)d_in[0];
    const int* tgt   = (const int*)d_in[1];
    const int* llen  = (const int*)d_in[2];
    const int* tlen  = (const int*)d_in[3];
    float* out = (float*)d_out;

    hipMemsetAsync(out, 0, sizeof(float), stream);
    rnnt_banded<<<BB, 256, 0, stream>>>(lp, tgt, llen, tlen, out);
}

// Round 3
// 34.647 us; speedup vs baseline: 2.3573x; 1.0594x over previous
//
#include <hip/hip_runtime.h>
#include <math.h>

#define TT 200
#define UU 200
#define VV 512
#define BB 8
#define NEGF (-1e30f)

// ---- DPP helpers (VALU pipe cross-lane, ~4-6cy dependent latency) ----
#define DPP_QUAD_XOR1       0xB1   // quad_perm [1,0,3,2]
#define DPP_QUAD_XOR2       0x4E   // quad_perm [2,3,0,1]
#define DPP_ROW_SHL1        0x101  // lane l <- l+1 (within row of 16)
#define DPP_ROW_SHR1        0x111  // lane l <- l-1
#define DPP_ROW_SHR2        0x112
#define DPP_ROW_SHR4        0x114
#define DPP_ROW_SHR8        0x118
#define DPP_ROW_MIRROR      0x140
#define DPP_ROW_HALF_MIRROR 0x141

template<int CTRL, bool ZERO>
__device__ __forceinline__ float fdpp(float src) {
    return __int_as_float(__builtin_amdgcn_update_dpp(
        __float_as_int(src), __float_as_int(src), CTRL, 0xF, 0xF, ZERO));
}

__device__ __forceinline__ float max16(float x) {
    x = fmaxf(x, fdpp<DPP_QUAD_XOR1, true>(x));
    x = fmaxf(x, fdpp<DPP_QUAD_XOR2, true>(x));
    x = fmaxf(x, fdpp<DPP_ROW_HALF_MIRROR, true>(x));
    x = fmaxf(x, fdpp<DPP_ROW_MIRROR, true>(x));
    return x;
}

// inclusive prefix sum within each 16-lane row (zero shifted in)
__device__ __forceinline__ float scan16(float x) {
    x += fdpp<DPP_ROW_SHR1, true>(x);
    x += fdpp<DPP_ROW_SHR2, true>(x);
    x += fdpp<DPP_ROW_SHR4, true>(x);
    x += fdpp<DPP_ROW_SHR8, true>(x);
    return x;
}

// Banded RNNT forward DP, linear-space (S-space) form.
// Q_t[l] = 2^(alpha_t[l] - Ce_t[l] - F_t);  Q_t = scan16(shift(Q_{t-1}) * P2_t)
// P2_t[l] = 2^(Ce_{t-1}[l+1] + Wc_t[l] - maxE_t) * validmasks  (precomputed)
// F_t = sum maxE_s;  exact pow2 renorm every 8 steps (Msum).
__global__ __launch_bounds__(256) void rnnt_banded(
    const float* __restrict__ lp,
    const int* __restrict__ targets,
    const int* __restrict__ logit_lengths,
    const int* __restrict__ target_lengths,
    float* __restrict__ out)
{
    __shared__ float Ls[TT][16];          // log2e * lp[t, t-5+l, tgt[u]]
    __shared__ float Ps[TT][16];          // log2e * lp[t, t-4+l, 0]
    __shared__ float Ce[TT * 16];         // exclusive prefix of Ls row
    __shared__ float P2[(TT + 1) * 16];   // step factors (pad row for prefetch)
    __shared__ float maxEs[TT + 1];       // per-step normalizer
    __shared__ int   tgt_s[UU];

    const int b   = blockIdx.x;
    const int tid = threadIdx.x;
    const float LOG2E = 1.4426950408889634f;

    const float* __restrict__ lpb = lp + (size_t)b * TT * UU * VV;

    if (tid < UU) tgt_s[tid] = targets[b * UU + tid];
    __syncthreads();

    // ---- Phase 1: gather band values (24 slots per t: 12 L, 12 pb) ----
    #pragma unroll
    for (int it = 0; it < 19; ++it) {
        int idx  = tid + it * 256;
        bool live = idx < TT * 24;
        int t = idx / 24;
        int r = idx - t * 24;
        bool isL = r < 12;
        int l = isL ? r : r - 12;
        int u = t + l + (isL ? -5 : -4);
        bool ok = live && (u >= 0) && (u < UU);
        float val = 0.0f;
        if (ok) {
            int v = isL ? tgt_s[u] : 0;
            val = lpb[((size_t)t * UU + u) * VV + v] * LOG2E;
        }
        if (live) {
            if (isL) Ls[t][l] = val;
            else     Ps[t][l] = val;
        }
    }
    __syncthreads();

    const int g = tid >> 4;     // 16 groups of 16 lanes
    const int l = tid & 15;

    // ---- Phase 1.5a: per-row exclusive prefix sums Ce ----
    for (int t = g; t < TT; t += 16) {
        float lv = (l < 12) ? Ls[t][l] : 0.0f;
        float cin = scan16(lv);
        Ce[t * 16 + l] = cin - lv;           // exclusive prefix
    }
    __syncthreads();

    // ---- Phase 1.5b: step factors P2, normalizers maxE ----
    // valid(t,l) := (l<=10) && 0 <= t-5+l < UU
    for (int t = 1 + g; t < TT; t += 16) {
        int u = t - 5 + l;
        bool vcur  = (l <= 10) && (u >= 0) && (u < UU);
        int up = (t - 1) - 5 + (l + 1);
        bool vprev = (l + 1 <= 10) && (up >= 0) && (up < UU);
        float cpn = Ce[(t - 1) * 16 + ((l + 1) & 15)];
        float ps  = (l < 12) ? Ps[t - 1][l] : 0.0f;
        float cec = Ce[t * 16 + l];
        float E = vcur ? (cpn + ps - cec) : NEGF;   // log2 units
        float mE = max16(E);
        float p2 = __builtin_amdgcn_exp2f(E - mE);
        if (!vprev) p2 = 0.0f;
        P2[t * 16 + l] = p2;
        if (l == 0) maxEs[t] = mE;
    }
    __syncthreads();

    if (tid >= 64) return;   // DP on wave 0 only (rows 1-3 duplicate row 0)

    const int tlen = logit_lengths[b];
    const int ulen = target_lengths[b];

    // init t=0: alpha_0[l] = Ce_0[l] for l in [5,10] else NEG  ->  Q = 1 / 0
    float Q    = (l >= 5 && l <= 10) ? 1.0f : 0.0f;
    float F    = 0.0f;     // sum of maxE (uniform)
    float Msum = 0.0f;     // renorm exponents (uniform)

    float p2 = P2[16 + l];
    float me = maxEs[1];

    for (int t = 1; t <= tlen; ++t) {
        float p2n = P2[(t + 1) * 16 + l];    // pad row at t=tlen: dead value
        float men = maxEs[t + 1];

        float sq = fdpp<DPP_ROW_SHL1, true>(Q);   // Q[l+1], 0 at row edge
        float e  = sq * p2;
        e = scan16(e);
        F += me;

        if ((t & 7) == 0) {                  // exact pow2 renorm
            float mq = max16(e);
            int ex;
            frexpf(mq, &ex);
            e = ldexpf(e, -ex);
            Msum += (float)ex;
        }
        Q = e;
        p2 = p2n; me = men;
    }

    // loss_b = -alpha[tlen][ulen]; owning lane l* = ulen - tlen + 5 in [0,5]
    int lstar = ulen - tlen + 5;
    if (tid == lstar) {
        float a = Ce[tlen * 16 + lstar] + F + Msum + __builtin_amdgcn_logf(Q);
        const float LN2 = 0.6931471805599453f;
        atomicAdd(out, -a * (LN2 / (float)BB));
    }
}

extern "C" void kernel_launch(void* const* d_in, const int* in_sizes, int n_in,
                              void* d_out, int out_size, void* d_ws, size_t ws_size,
                              hipStream_t stream) {
    const float* lp  = (const float*)d_in[0];
    const int* tgt   = (const int*)d_in[1];
    const int* llen  = (const int*)d_in[2];
    const int* tlen  = (const int*)d_in[3];
    float* out = (float*)d_out;
    (void)d_ws; (void)ws_size; (void)in_sizes; (void)n_in; (void)out_size;

    hipMemsetAsync(out, 0, sizeof(float), stream);
    rnnt_banded<<<BB, 256, 0, stream>>>(lp, tgt, llen, tlen, out);
}

// Round 4
// 26.278 us; speedup vs baseline: 3.1080x; 1.3185x over previous
//
#include <hip/hip_runtime.h>
#include <math.h>

#define TT 200
#define UU 200
#define VV 512
#define BB 8
#define NEGF (-1e30f)
#define P2STRIDE 212   // dwords; 848B row stride: 16B-aligned, <=2-way bank alias

// ---- DPP helpers (VALU pipe cross-lane) ----
#define DPP_QUAD_XOR1       0xB1
#define DPP_QUAD_XOR2       0x4E
#define DPP_ROW_SHL1        0x101
#define DPP_ROW_SHR1        0x111
#define DPP_ROW_SHR2        0x112
#define DPP_ROW_SHR4        0x114
#define DPP_ROW_SHR8        0x118
#define DPP_ROW_MIRROR      0x140
#define DPP_ROW_HALF_MIRROR 0x141

template<int CTRL, bool ZERO>
__device__ __forceinline__ float fdpp(float src) {
    return __int_as_float(__builtin_amdgcn_update_dpp(
        __float_as_int(src), __float_as_int(src), CTRL, 0xF, 0xF, ZERO));
}

__device__ __forceinline__ float max16(float x) {
    x = fmaxf(x, fdpp<DPP_QUAD_XOR1, true>(x));
    x = fmaxf(x, fdpp<DPP_QUAD_XOR2, true>(x));
    x = fmaxf(x, fdpp<DPP_ROW_HALF_MIRROR, true>(x));
    x = fmaxf(x, fdpp<DPP_ROW_MIRROR, true>(x));
    return x;
}

__device__ __forceinline__ float scan16(float x) {
    x += fdpp<DPP_ROW_SHR1, true>(x);
    x += fdpp<DPP_ROW_SHR2, true>(x);
    x += fdpp<DPP_ROW_SHR4, true>(x);
    x += fdpp<DPP_ROW_SHR8, true>(x);
    return x;
}

// Banded RNNT forward DP, linear-space form with transposed step factors.
// Q_t = scan16( shift(Q_{t-1}) * P2_t );  alpha = Ce + F + Msum + log2(Q)
__global__ __launch_bounds__(256) void rnnt_banded(
    const float* __restrict__ lp,
    const int* __restrict__ targets,
    const int* __restrict__ logit_lengths,
    const int* __restrict__ target_lengths,
    float* __restrict__ out)
{
    __shared__ float Ls[TT][16];
    __shared__ float Ps[TT][16];
    __shared__ float Ce[TT * 16];
    __shared__ float P2S[16][P2STRIDE];   // P2S[l][t-1] = step factor
    __shared__ float maxEs[TT + 1];
    __shared__ float redW[4];
    __shared__ int   tgt_s[UU];

    const int b   = blockIdx.x;
    const int tid = threadIdx.x;
    const float LOG2E = 1.4426950408889634f;

    const float* __restrict__ lpb = lp + (size_t)b * TT * UU * VV;

    if (tid < UU) tgt_s[tid] = targets[b * UU + tid];
    __syncthreads();

    // ---- Phase 1: gather band values (24 slots per t: 12 L, 12 pb) ----
    #pragma unroll
    for (int it = 0; it < 19; ++it) {
        int idx  = tid + it * 256;
        bool live = idx < TT * 24;
        int t = idx / 24;
        int r = idx - t * 24;
        bool isL = r < 12;
        int l = isL ? r : r - 12;
        int u = t + l + (isL ? -5 : -4);
        bool ok = live && (u >= 0) && (u < UU);
        float val = 0.0f;
        if (ok) {
            int v = isL ? tgt_s[u] : 0;
            val = lpb[((size_t)t * UU + u) * VV + v] * LOG2E;
        }
        if (live) {
            if (isL) Ls[t][l] = val;
            else     Ps[t][l] = val;
        }
    }
    __syncthreads();

    const int g = tid >> 4;
    const int l = tid & 15;

    // ---- Phase 1.5a: Ce scans; zero P2S tail (idx 196..211, overwritten <=198) ----
    for (int t = g; t < TT; t += 16) {
        float lv = (l < 12) ? Ls[t][l] : 0.0f;
        float cin = scan16(lv);
        Ce[t * 16 + l] = cin - lv;
    }
    P2S[tid >> 4][196 + (tid & 15)] = 0.0f;
    __syncthreads();

    // ---- Phase 1.5b: step factors P2S[l][t-1], normalizers maxEs[t] ----
    for (int t = 1 + g; t < TT; t += 16) {
        int u = t - 5 + l;
        bool vcur  = (l <= 10) && (u >= 0) && (u < UU);
        int up = (t - 1) - 5 + (l + 1);
        bool vprev = (l + 1 <= 10) && (up >= 0) && (up < UU);
        float cpn = Ce[(t - 1) * 16 + ((l + 1) & 15)];
        float ps  = (l < 12) ? Ps[t - 1][l] : 0.0f;
        float cec = Ce[t * 16 + l];
        float E = vcur ? (cpn + ps - cec) : NEGF;
        float mE = max16(E);
        float p2 = __builtin_amdgcn_exp2f(E - mE);
        if (!vprev) p2 = 0.0f;
        P2S[l][t - 1] = p2;
        if (l == 0) maxEs[t] = mE;
    }
    __syncthreads();

    const int tlen = logit_lengths[b];
    const int ulen = target_lengths[b];

    // ---- F = sum_{t=1..tlen} maxEs[t]  (block reduction, off DP path) ----
    {
        float mv = (tid >= 1 && tid <= tlen) ? maxEs[tid] : 0.0f;
        #pragma unroll
        for (int d = 32; d; d >>= 1) mv += __shfl_xor(mv, d, 64);
        if ((tid & 63) == 0) redW[tid >> 6] = mv;
    }
    __syncthreads();

    if (tid >= 64) return;   // DP on wave 0 only

    float Q  = (l >= 5 && l <= 10) ? 1.0f : 0.0f;
    float qs = 1.0f;
    int   Msum = 0, msCap = 0;

    const float* __restrict__ rowp = &P2S[l][0];
    float4 A  = *(const float4*)(rowp + 0);
    float4 Bv = *(const float4*)(rowp + 4);

#define STEP(PV, TCUR) do {                          \
        float sq_ = fdpp<DPP_ROW_SHL1, true>(Q);     \
        Q = scan16(sq_ * (PV));                      \
        if ((TCUR) == tlen) { qs = Q; msCap = Msum; }\
    } while (0)

    for (int c = 0; c < 25; ++c) {
        float4 An, Bn;
        if (c < 24) {
            An = *(const float4*)(rowp + 8 * c + 8);
            Bn = *(const float4*)(rowp + 8 * c + 12);
        } else { An = A; Bn = Bv; }
        int t0 = 8 * c;
        STEP(A.x,  t0 + 1); STEP(A.y,  t0 + 2);
        STEP(A.z,  t0 + 3); STEP(A.w,  t0 + 4);
        STEP(Bv.x, t0 + 5); STEP(Bv.y, t0 + 6);
        STEP(Bv.z, t0 + 7); STEP(Bv.w, t0 + 8);
        // exact pow2 renorm from row total (lane 15 of inclusive scan)
        int qb = __builtin_amdgcn_readlane(__float_as_int(Q), 15);
        int ex = ((qb >> 23) & 0xFF) - 127;
        Q = ldexpf(Q, -ex);
        Msum += ex;
        A = An; Bv = Bn;
    }
#undef STEP

    // loss_b = -alpha[tlen][ulen]; owning lane l* = ulen - tlen + 5 in [0,5]
    int lstar = ulen - tlen + 5;
    if (tid == lstar) {
        float F = redW[0] + redW[1] + redW[2] + redW[3];
        float a = Ce[tlen * 16 + lstar] + F + (float)msCap
                + __builtin_amdgcn_logf(qs);
        const float LN2 = 0.6931471805599453f;
        atomicAdd(out, -a * (LN2 / (float)BB));
    }
}

extern "C" void kernel_launch(void* const* d_in, const int* in_sizes, int n_in,
                              void* d_out, int out_size, void* d_ws, size_t ws_size,
                              hipStream_t stream) {
    const float* lp  = (const float*)d_in[0];
    const int* tgt   = (const int*)d_in[1];
    const int* llen  = (const int*)d_in[2];
    const int* tlen  = (const int*)d_in[3];
    float* out = (float*)d_out;
    (void)d_ws; (void)ws_size; (void)in_sizes; (void)n_in; (void)out_size;

    hipMemsetAsync(out, 0, sizeof(float), stream);
    rnnt_banded<<<BB, 256, 0, stream>>>(lp, tgt, llen, tlen, out);
}